// Round 9
// baseline (17524.704 us; speedup 1.0000x reference)
//
#include <hip/hip_runtime.h>
#include <hip/hip_bf16.h>

// Problem constants: N=8192, Din=1024, H=1024, 4H=4096.
#define NSTEP 8192
#define DIN   1024
#define HDIM  1024
#define G4    4096

typedef float f32x4 __attribute__((ext_vector_type(4)));

// ---------------------------------------------------------------------------
// Phase A: x_gates[n][m] = dot(xs[n,:], W_ih[m,:]) + b_ih[m] + b_hh[m]
// ---------------------------------------------------------------------------
__global__ __launch_bounds__(256) void gemm_xgates(
    const float* __restrict__ xs,    // [8192,1024]
    const float* __restrict__ Wih,   // [4096,1024]
    const float* __restrict__ bih,   // [4096]
    const float* __restrict__ bhh,   // [4096]
    float* __restrict__ xg)          // [8192,4096]
{
    __shared__ float a_s[32][68];
    __shared__ float b_s[32][68];

    const int bm = blockIdx.x;
    const int bn = blockIdx.y;
    const int tid = threadIdx.x;
    const int tx = tid & 15;
    const int ty = tid >> 4;

    float acc[4][4] = {};

    for (int k0 = 0; k0 < DIN; k0 += 32) {
        #pragma unroll
        for (int s = tid; s < 512; s += 256) {
            const int r  = s >> 3;
            const int kk = (s & 7) << 2;
            const float4 av = *(const float4*)&xs[(size_t)(bn * 64 + r) * DIN + k0 + kk];
            a_s[kk + 0][r] = av.x; a_s[kk + 1][r] = av.y;
            a_s[kk + 2][r] = av.z; a_s[kk + 3][r] = av.w;
            const float4 bv = *(const float4*)&Wih[(size_t)(bm * 64 + r) * DIN + k0 + kk];
            b_s[kk + 0][r] = bv.x; b_s[kk + 1][r] = bv.y;
            b_s[kk + 2][r] = bv.z; b_s[kk + 3][r] = bv.w;
        }
        __syncthreads();

        #pragma unroll
        for (int k = 0; k < 32; ++k) {
            const float4 a = *(const float4*)&a_s[k][ty << 2];
            const float4 b = *(const float4*)&b_s[k][tx << 2];
            acc[0][0] = fmaf(a.x, b.x, acc[0][0]); acc[0][1] = fmaf(a.x, b.y, acc[0][1]);
            acc[0][2] = fmaf(a.x, b.z, acc[0][2]); acc[0][3] = fmaf(a.x, b.w, acc[0][3]);
            acc[1][0] = fmaf(a.y, b.x, acc[1][0]); acc[1][1] = fmaf(a.y, b.y, acc[1][1]);
            acc[1][2] = fmaf(a.y, b.z, acc[1][2]); acc[1][3] = fmaf(a.y, b.w, acc[1][3]);
            acc[2][0] = fmaf(a.z, b.x, acc[2][0]); acc[2][1] = fmaf(a.z, b.y, acc[2][1]);
            acc[2][2] = fmaf(a.z, b.z, acc[2][2]); acc[2][3] = fmaf(a.z, b.w, acc[2][3]);
            acc[3][0] = fmaf(a.w, b.x, acc[3][0]); acc[3][1] = fmaf(a.w, b.y, acc[3][1]);
            acc[3][2] = fmaf(a.w, b.z, acc[3][2]); acc[3][3] = fmaf(a.w, b.w, acc[3][3]);
        }
        __syncthreads();
    }

    const int m0 = bm * 64 + (tx << 2);
    const float4 bias = make_float4(bih[m0 + 0] + bhh[m0 + 0],
                                    bih[m0 + 1] + bhh[m0 + 1],
                                    bih[m0 + 2] + bhh[m0 + 2],
                                    bih[m0 + 3] + bhh[m0 + 3]);
    #pragma unroll
    for (int u = 0; u < 4; ++u) {
        const int n = bn * 64 + (ty << 2) + u;
        float4 v = make_float4(acc[u][0] + bias.x, acc[u][1] + bias.y,
                               acc[u][2] + bias.z, acc[u][3] + bias.w);
        *(float4*)&xg[(size_t)n * G4 + m0] = v;
    }
}

// ---------------------------------------------------------------------------
// Phase B: persistent recurrence. 128 WGs x 512 threads (cooperative).
// R7/R8 structure (wave-autonomous rows, W pinned in VGPRs, data-as-flag
// slots) with ONE change: COALESCED PUBLISH. R8 evidence: WRITE_SIZE 295MB
// (36KB/step vs 12 ideal) — each WG's 64B slot-line was written as 8
// separate 8B write-through stores from 8 different waves at skewed times;
// partial-line agent writes serialize at the coherence point and the
// consumer's step is gated by the LAST-visible slot (~600-800cyc).
// Fix: each wave's lane0 ds_writes its packed {tag,h} to an 8-entry LDS
// staging array; lgkm barrier; wave 0 lanes 0-7 issue the WG's whole 64B
// slot-line as ONE coalesced 8-lane store (and ys as one 32B store).
// Barriers are raw lgkm-only (R8): no vmcnt drain on the critical path.
// ---------------------------------------------------------------------------
#define REC_G 128
#define REC_T 512
#define HPW   8

#define STEP_BARRIER() do {                                   \
    asm volatile("s_waitcnt lgkmcnt(0)" ::: "memory");        \
    __builtin_amdgcn_s_barrier();                             \
    asm volatile("" ::: "memory");                            \
} while (0)

__global__ __attribute__((amdgpu_waves_per_eu(2, 2)))
__launch_bounds__(REC_T) void lstm_rec(
    const float* __restrict__ xg,    // [NSTEP, 4096]
    const float* __restrict__ Whh,   // [4096, 1024]
    const float* __restrict__ h0,    // [1024]
    const float* __restrict__ c0,    // [1024]
    float* __restrict__ ys,          // [NSTEP, 1024]
    unsigned long long* slots)       // [2][1024] ws, memset 0 pre-launch
{
    __shared__ float h_lds[2][HDIM];
    __shared__ unsigned long long pub[HPW];   // per-wave packed {tag,h}

    const int tid   = threadIdx.x;
    const int lane  = tid & 63;
    const int wv    = tid >> 6;           // 0..7
    const int wg    = blockIdx.x;         // 0..127
    const int jglob = wg * HPW + wv;      // this wave's hidden index

    // ---- stage W: w[r*4+i] = Whh[r*HDIM + jglob][4*(lane+64i) .. +3] ----
    f32x4 w[16];
    #pragma unroll
    for (int r = 0; r < 4; ++r) {
        const float* wb = Whh + (size_t)(r * HDIM + jglob) * HDIM;
        #pragma unroll
        for (int i = 0; i < 4; ++i)
            w[r * 4 + i] = *(const f32x4*)(wb + ((lane + (i << 6)) << 2));
    }
    asm volatile("" : "+v"(w[0]), "+v"(w[1]), "+v"(w[2]), "+v"(w[3]),
                      "+v"(w[4]), "+v"(w[5]), "+v"(w[6]), "+v"(w[7]));
    asm volatile("" : "+v"(w[8]), "+v"(w[9]), "+v"(w[10]), "+v"(w[11]),
                      "+v"(w[12]), "+v"(w[13]), "+v"(w[14]), "+v"(w[15]));

    // ---- init: h0 -> buffer 0; c + xg rows 0,1 redundant on all lanes ----
    ((float2*)h_lds[0])[tid] = ((const float2*)h0)[tid];
    float c_reg = c0[jglob];                       // wave-broadcast load
    float xc0 = xg[0 * HDIM + jglob];
    float xc1 = xg[1 * HDIM + jglob];
    float xc2 = xg[2 * HDIM + jglob];
    float xc3 = xg[3 * HDIM + jglob];
    float xn0 = xg[(size_t)G4 + 0 * HDIM + jglob];
    float xn1 = xg[(size_t)G4 + 1 * HDIM + jglob];
    float xn2 = xg[(size_t)G4 + 2 * HDIM + jglob];
    float xn3 = xg[(size_t)G4 + 3 * HDIM + jglob];
    __syncthreads();

    for (int t = 0; t < NSTEP; ++t) {
        const f32x4* hb = (const f32x4*)h_lds[t & 1];

        // ---- dot: W in VGPRs, h from LDS (4 ds_read_b128, consecutive) ----
        float a0 = 0.f, a1 = 0.f, a2 = 0.f, a3 = 0.f;
        #pragma unroll
        for (int i = 0; i < 4; ++i) {
            const f32x4 hv = hb[lane + (i << 6)];
            a0 = fmaf(w[0  + i].x, hv.x, a0); a0 = fmaf(w[0  + i].y, hv.y, a0);
            a0 = fmaf(w[0  + i].z, hv.z, a0); a0 = fmaf(w[0  + i].w, hv.w, a0);
            a1 = fmaf(w[4  + i].x, hv.x, a1); a1 = fmaf(w[4  + i].y, hv.y, a1);
            a1 = fmaf(w[4  + i].z, hv.z, a1); a1 = fmaf(w[4  + i].w, hv.w, a1);
            a2 = fmaf(w[8  + i].x, hv.x, a2); a2 = fmaf(w[8  + i].y, hv.y, a2);
            a2 = fmaf(w[8  + i].z, hv.z, a2); a2 = fmaf(w[8  + i].w, hv.w, a2);
            a3 = fmaf(w[12 + i].x, hv.x, a3); a3 = fmaf(w[12 + i].y, hv.y, a3);
            a3 = fmaf(w[12 + i].z, hv.z, a3); a3 = fmaf(w[12 + i].w, hv.w, a3);
        }
        #pragma unroll
        for (int m = 1; m < 64; m <<= 1) {
            a0 += __shfl_xor(a0, m);
            a1 += __shfl_xor(a1, m);
            a2 += __shfl_xor(a2, m);
            a3 += __shfl_xor(a3, m);
        }

        // ---- gating: redundant on all 64 lanes (same cycles as 1 lane) ----
        const float gi = a0 + xc0;
        const float gf = a1 + xc1;
        const float gg = a2 + xc2;
        const float go = a3 + xc3;
        const float i_ = 1.f / (1.f + __expf(-gi));
        const float f_ = 1.f / (1.f + __expf(-gf));
        const float g_ = 2.f / (1.f + __expf(-2.f * gg)) - 1.f;
        const float o_ = 1.f / (1.f + __expf(-go));
        c_reg = f_ * c_reg + i_ * g_;
        const float h_ = o_ * (2.f / (1.f + __expf(-2.f * c_reg)) - 1.f);

        // ---- stage packed {tag,h} into LDS (one ds_write_b64 per wave) ----
        const unsigned long long pk =
            ((unsigned long long)(unsigned)(t + 1) << 32) |
            (unsigned long long)__float_as_uint(h_);
        if (lane == 0) pub[wv] = pk;
        STEP_BARRIER();   // A: pub visible to wave 0 (lgkm only)

        // ---- wave 0 publishes the WG's whole 64B slot-line coalesced ----
        if (tid < HPW) {
            const unsigned long long pr = pub[tid];
            ys[(size_t)t * HDIM + (wg << 3) + tid] =
                __uint_as_float((unsigned)pr);               // 32B coalesced
            if (t + 1 < NSTEP)
                __hip_atomic_store(&slots[((t + 1) & 1) * HDIM + (wg << 3) + tid],
                                   pr, __ATOMIC_RELAXED,
                                   __HIP_MEMORY_SCOPE_AGENT); // 64B coalesced
        }

        // ---- off critical path: rotate xg prefetch, fetch t+2 ----
        xc0 = xn0; xc1 = xn1; xc2 = xn2; xc3 = xn3;
        if (t + 2 < NSTEP) {
            const size_t xb = (size_t)(t + 2) * G4 + jglob;
            xn0 = xg[xb + 0 * HDIM];
            xn1 = xg[xb + 1 * HDIM];
            xn2 = xg[xb + 2 * HDIM];
            xn3 = xg[xb + 3 * HDIM];
        }
        if (t + 1 == NSTEP) break;

        // ---- poll own 2 slots (both loads in flight per iteration) ----
        {
            const unsigned long long* sp = slots + ((t + 1) & 1) * HDIM;
            const unsigned long long want =
                (unsigned long long)(unsigned)(t + 1) << 32;
            unsigned long long s0, s1;
            do {
                s0 = __hip_atomic_load(&sp[2 * tid], __ATOMIC_RELAXED,
                                       __HIP_MEMORY_SCOPE_AGENT);
                s1 = __hip_atomic_load(&sp[2 * tid + 1], __ATOMIC_RELAXED,
                                       __HIP_MEMORY_SCOPE_AGENT);
            } while (s0 < want || s1 < want);
            float2 hv;
            hv.x = __uint_as_float((unsigned)s0);
            hv.y = __uint_as_float((unsigned)s1);
            ((float2*)h_lds[(t + 1) & 1])[tid] = hv;
        }
        STEP_BARRIER();   // B: h_lds ready for next step (lgkm only)
    }
}

// ---------------------------------------------------------------------------
extern "C" void kernel_launch(void* const* d_in, const int* in_sizes, int n_in,
                              void* d_out, int out_size, void* d_ws, size_t ws_size,
                              hipStream_t stream) {
    const float* xs  = (const float*)d_in[0];
    const float* Wih = (const float*)d_in[1];
    const float* Whh = (const float*)d_in[2];
    const float* bih = (const float*)d_in[3];
    const float* bhh = (const float*)d_in[4];
    const float* h0  = (const float*)d_in[5];
    const float* c0  = (const float*)d_in[6];
    float* ys = (float*)d_out;

    const size_t XG_BYTES = (size_t)NSTEP * G4 * sizeof(float);   // 134 MB
    float* xg = (float*)d_ws;
    unsigned long long* slots =
        (unsigned long long*)((char*)d_ws + XG_BYTES);            // 16 KB

    // kill stale tags from previous graph replay (deterministic per call)
    hipMemsetAsync(slots, 0, 2 * HDIM * sizeof(unsigned long long), stream);

    dim3 gridA(G4 / 64, NSTEP / 64);
    gemm_xgates<<<gridA, 256, 0, stream>>>(xs, Wih, bih, bhh, xg);

    void* args[] = {(void*)&xg, (void*)&Whh, (void*)&h0, (void*)&c0,
                    (void*)&ys, (void*)&slots};
    hipLaunchCooperativeKernel((void*)lstm_rec, dim3(REC_G), dim3(REC_T),
                               args, 0, stream);
}

// Round 10
// 13760.236 us; speedup vs baseline: 1.2736x; 1.2736x over previous
//
#include <hip/hip_runtime.h>
#include <hip/hip_bf16.h>

// Problem constants: N=8192, Din=1024, H=1024, 4H=4096.
#define NSTEP 8192
#define DIN   1024
#define HDIM  1024
#define G4    4096

typedef float f32x4 __attribute__((ext_vector_type(4)));

// ---------------------------------------------------------------------------
// Phase A: x_gates[n][m] = dot(xs[n,:], W_ih[m,:]) + b_ih[m] + b_hh[m]
// ---------------------------------------------------------------------------
__global__ __launch_bounds__(256) void gemm_xgates(
    const float* __restrict__ xs,    // [8192,1024]
    const float* __restrict__ Wih,   // [4096,1024]
    const float* __restrict__ bih,   // [4096]
    const float* __restrict__ bhh,   // [4096]
    float* __restrict__ xg)          // [8192,4096]
{
    __shared__ float a_s[32][68];
    __shared__ float b_s[32][68];

    const int bm = blockIdx.x;
    const int bn = blockIdx.y;
    const int tid = threadIdx.x;
    const int tx = tid & 15;
    const int ty = tid >> 4;

    float acc[4][4] = {};

    for (int k0 = 0; k0 < DIN; k0 += 32) {
        #pragma unroll
        for (int s = tid; s < 512; s += 256) {
            const int r  = s >> 3;
            const int kk = (s & 7) << 2;
            const float4 av = *(const float4*)&xs[(size_t)(bn * 64 + r) * DIN + k0 + kk];
            a_s[kk + 0][r] = av.x; a_s[kk + 1][r] = av.y;
            a_s[kk + 2][r] = av.z; a_s[kk + 3][r] = av.w;
            const float4 bv = *(const float4*)&Wih[(size_t)(bm * 64 + r) * DIN + k0 + kk];
            b_s[kk + 0][r] = bv.x; b_s[kk + 1][r] = bv.y;
            b_s[kk + 2][r] = bv.z; b_s[kk + 3][r] = bv.w;
        }
        __syncthreads();

        #pragma unroll
        for (int k = 0; k < 32; ++k) {
            const float4 a = *(const float4*)&a_s[k][ty << 2];
            const float4 b = *(const float4*)&b_s[k][tx << 2];
            acc[0][0] = fmaf(a.x, b.x, acc[0][0]); acc[0][1] = fmaf(a.x, b.y, acc[0][1]);
            acc[0][2] = fmaf(a.x, b.z, acc[0][2]); acc[0][3] = fmaf(a.x, b.w, acc[0][3]);
            acc[1][0] = fmaf(a.y, b.x, acc[1][0]); acc[1][1] = fmaf(a.y, b.y, acc[1][1]);
            acc[1][2] = fmaf(a.y, b.z, acc[1][2]); acc[1][3] = fmaf(a.y, b.w, acc[1][3]);
            acc[2][0] = fmaf(a.z, b.x, acc[2][0]); acc[2][1] = fmaf(a.z, b.y, acc[2][1]);
            acc[2][2] = fmaf(a.z, b.z, acc[2][2]); acc[2][3] = fmaf(a.z, b.w, acc[2][3]);
            acc[3][0] = fmaf(a.w, b.x, acc[3][0]); acc[3][1] = fmaf(a.w, b.y, acc[3][1]);
            acc[3][2] = fmaf(a.w, b.z, acc[3][2]); acc[3][3] = fmaf(a.w, b.w, acc[3][3]);
        }
        __syncthreads();
    }

    const int m0 = bm * 64 + (tx << 2);
    const float4 bias = make_float4(bih[m0 + 0] + bhh[m0 + 0],
                                    bih[m0 + 1] + bhh[m0 + 1],
                                    bih[m0 + 2] + bhh[m0 + 2],
                                    bih[m0 + 3] + bhh[m0 + 3]);
    #pragma unroll
    for (int u = 0; u < 4; ++u) {
        const int n = bn * 64 + (ty << 2) + u;
        float4 v = make_float4(acc[u][0] + bias.x, acc[u][1] + bias.y,
                               acc[u][2] + bias.z, acc[u][3] + bias.w);
        *(float4*)&xg[(size_t)n * G4 + m0] = v;
    }
}

// ---------------------------------------------------------------------------
// Phase B: persistent recurrence. 128 WGs x 512 threads (cooperative).
// R8 structure (wave-autonomous rows: wave wv owns all 4 gate rows of
// j = wg*8+wv; W pinned in VGPRs via waves_per_eu(2,2); data-as-flag slot
// exchange with per-wave lane0 publish-ASAP; raw lgkm-only barrier) with
// ONE change: the 64-lane reduction.
// R9 evidence: 6-stage __shfl_xor butterfly = 6 DEPENDENT DS-pipe ops
// (~120cyc each, m117) ≈ 700cyc of reduce latency on the critical path.
// Replaced with VALU-rate DPP (quad_perm xor1/xor2, row_half_mirror,
// row_mirror -> 16-lane group sums, ~2-4cyc each) + 4x v_readlane
// (lanes 0/16/32/48) + adds -> all 4 gate totals uniform in every lane.
// Zero DS-pipe ops in the reduce; gating unchanged (uniform inputs).
// (R9's coalesced publish reverted: WRITE_SIZE fell 295->98MB but dur rose
// — write amplification was off the critical path; the added barrier
// serialized publish behind the slowest wave.)
// ---------------------------------------------------------------------------
#define REC_G 128
#define REC_T 512
#define HPW   8

#define STEP_BARRIER() do {                                   \
    asm volatile("s_waitcnt lgkmcnt(0)" ::: "memory");        \
    __builtin_amdgcn_s_barrier();                             \
    asm volatile("" ::: "memory");                            \
} while (0)

// dst = x + dpp_mov(x, CTRL); all rows/banks, bound_ctrl=0-fill.
#define DPP_ADD(x, ctrl) \
    ((x) + __int_as_float(__builtin_amdgcn_update_dpp( \
        0, __float_as_int(x), (ctrl), 0xF, 0xF, true)))

#define RDLANE(x, l) \
    __int_as_float(__builtin_amdgcn_readlane(__float_as_int(x), (l)))

__global__ __attribute__((amdgpu_waves_per_eu(2, 2)))
__launch_bounds__(REC_T) void lstm_rec(
    const float* __restrict__ xg,    // [NSTEP, 4096]
    const float* __restrict__ Whh,   // [4096, 1024]
    const float* __restrict__ h0,    // [1024]
    const float* __restrict__ c0,    // [1024]
    float* __restrict__ ys,          // [NSTEP, 1024]
    unsigned long long* slots)       // [2][1024] ws, memset 0 pre-launch
{
    __shared__ float h_lds[2][HDIM];

    const int tid   = threadIdx.x;
    const int lane  = tid & 63;
    const int wv    = tid >> 6;           // 0..7
    const int wg    = blockIdx.x;         // 0..127
    const int jglob = wg * HPW + wv;      // this wave's hidden index

    // ---- stage W: w[r*4+i] = Whh[r*HDIM + jglob][4*(lane+64i) .. +3] ----
    f32x4 w[16];
    #pragma unroll
    for (int r = 0; r < 4; ++r) {
        const float* wb = Whh + (size_t)(r * HDIM + jglob) * HDIM;
        #pragma unroll
        for (int i = 0; i < 4; ++i)
            w[r * 4 + i] = *(const f32x4*)(wb + ((lane + (i << 6)) << 2));
    }
    asm volatile("" : "+v"(w[0]), "+v"(w[1]), "+v"(w[2]), "+v"(w[3]),
                      "+v"(w[4]), "+v"(w[5]), "+v"(w[6]), "+v"(w[7]));
    asm volatile("" : "+v"(w[8]), "+v"(w[9]), "+v"(w[10]), "+v"(w[11]),
                      "+v"(w[12]), "+v"(w[13]), "+v"(w[14]), "+v"(w[15]));

    // ---- init: h0 -> buffer 0; c + xg rows 0,1 redundant on all lanes ----
    ((float2*)h_lds[0])[tid] = ((const float2*)h0)[tid];
    float c_reg = c0[jglob];                       // wave-broadcast load
    float xc0 = xg[0 * HDIM + jglob];
    float xc1 = xg[1 * HDIM + jglob];
    float xc2 = xg[2 * HDIM + jglob];
    float xc3 = xg[3 * HDIM + jglob];
    float xn0 = xg[(size_t)G4 + 0 * HDIM + jglob];
    float xn1 = xg[(size_t)G4 + 1 * HDIM + jglob];
    float xn2 = xg[(size_t)G4 + 2 * HDIM + jglob];
    float xn3 = xg[(size_t)G4 + 3 * HDIM + jglob];
    __syncthreads();

    for (int t = 0; t < NSTEP; ++t) {
        const f32x4* hb = (const f32x4*)h_lds[t & 1];

        // ---- dot: W in VGPRs, h from LDS (4 ds_read_b128, consecutive) ----
        float a0 = 0.f, a1 = 0.f, a2 = 0.f, a3 = 0.f;
        #pragma unroll
        for (int i = 0; i < 4; ++i) {
            const f32x4 hv = hb[lane + (i << 6)];
            a0 = fmaf(w[0  + i].x, hv.x, a0); a0 = fmaf(w[0  + i].y, hv.y, a0);
            a0 = fmaf(w[0  + i].z, hv.z, a0); a0 = fmaf(w[0  + i].w, hv.w, a0);
            a1 = fmaf(w[4  + i].x, hv.x, a1); a1 = fmaf(w[4  + i].y, hv.y, a1);
            a1 = fmaf(w[4  + i].z, hv.z, a1); a1 = fmaf(w[4  + i].w, hv.w, a1);
            a2 = fmaf(w[8  + i].x, hv.x, a2); a2 = fmaf(w[8  + i].y, hv.y, a2);
            a2 = fmaf(w[8  + i].z, hv.z, a2); a2 = fmaf(w[8  + i].w, hv.w, a2);
            a3 = fmaf(w[12 + i].x, hv.x, a3); a3 = fmaf(w[12 + i].y, hv.y, a3);
            a3 = fmaf(w[12 + i].z, hv.z, a3); a3 = fmaf(w[12 + i].w, hv.w, a3);
        }

        // ---- reduce: 4 DPP stages (VALU-rate, within 16-lane groups) ----
        a0 = DPP_ADD(a0, 0xB1);  a1 = DPP_ADD(a1, 0xB1);   // quad_perm xor1
        a2 = DPP_ADD(a2, 0xB1);  a3 = DPP_ADD(a3, 0xB1);
        a0 = DPP_ADD(a0, 0x4E);  a1 = DPP_ADD(a1, 0x4E);   // quad_perm xor2
        a2 = DPP_ADD(a2, 0x4E);  a3 = DPP_ADD(a3, 0x4E);
        a0 = DPP_ADD(a0, 0x141); a1 = DPP_ADD(a1, 0x141);  // row_half_mirror
        a2 = DPP_ADD(a2, 0x141); a3 = DPP_ADD(a3, 0x141);
        a0 = DPP_ADD(a0, 0x140); a1 = DPP_ADD(a1, 0x140);  // row_mirror
        a2 = DPP_ADD(a2, 0x140); a3 = DPP_ADD(a3, 0x140);
        // cross-group totals via readlane (uniform in every lane)
        const float t0 = (RDLANE(a0, 0) + RDLANE(a0, 16))
                       + (RDLANE(a0, 32) + RDLANE(a0, 48));
        const float t1 = (RDLANE(a1, 0) + RDLANE(a1, 16))
                       + (RDLANE(a1, 32) + RDLANE(a1, 48));
        const float t2 = (RDLANE(a2, 0) + RDLANE(a2, 16))
                       + (RDLANE(a2, 32) + RDLANE(a2, 48));
        const float t3 = (RDLANE(a3, 0) + RDLANE(a3, 16))
                       + (RDLANE(a3, 32) + RDLANE(a3, 48));

        // ---- gating: uniform inputs, redundant on all 64 lanes ----
        const float gi = t0 + xc0;
        const float gf = t1 + xc1;
        const float gg = t2 + xc2;
        const float go = t3 + xc3;
        const float i_ = 1.f / (1.f + __expf(-gi));
        const float f_ = 1.f / (1.f + __expf(-gf));
        const float g_ = 2.f / (1.f + __expf(-2.f * gg)) - 1.f;
        const float o_ = 1.f / (1.f + __expf(-go));
        c_reg = f_ * c_reg + i_ * g_;
        const float h_ = o_ * (2.f / (1.f + __expf(-2.f * c_reg)) - 1.f);

        // ---- publish ASAP (lane 0), then off-critical-path work ----
        if (lane == 0) {
            if (t + 1 < NSTEP) {
                const unsigned long long pk =
                    ((unsigned long long)(unsigned)(t + 1) << 32) |
                    (unsigned long long)__float_as_uint(h_);
                __hip_atomic_store(&slots[((t + 1) & 1) * HDIM + jglob], pk,
                                   __ATOMIC_RELAXED, __HIP_MEMORY_SCOPE_AGENT);
            }
            ys[(size_t)t * HDIM + jglob] = h_;
        }
        xc0 = xn0; xc1 = xn1; xc2 = xn2; xc3 = xn3;
        if (t + 2 < NSTEP) {
            const size_t xb = (size_t)(t + 2) * G4 + jglob;
            xn0 = xg[xb + 0 * HDIM];
            xn1 = xg[xb + 1 * HDIM];
            xn2 = xg[xb + 2 * HDIM];
            xn3 = xg[xb + 3 * HDIM];
        }
        if (t + 1 == NSTEP) break;

        // ---- poll own 2 slots (both loads in flight per iteration) ----
        {
            const unsigned long long* sp = slots + ((t + 1) & 1) * HDIM;
            const unsigned long long want =
                (unsigned long long)(unsigned)(t + 1) << 32;
            unsigned long long s0, s1;
            do {
                s0 = __hip_atomic_load(&sp[2 * tid], __ATOMIC_RELAXED,
                                       __HIP_MEMORY_SCOPE_AGENT);
                s1 = __hip_atomic_load(&sp[2 * tid + 1], __ATOMIC_RELAXED,
                                       __HIP_MEMORY_SCOPE_AGENT);
            } while (s0 < want || s1 < want);
            float2 hv;
            hv.x = __uint_as_float((unsigned)s0);
            hv.y = __uint_as_float((unsigned)s1);
            ((float2*)h_lds[(t + 1) & 1])[tid] = hv;
        }
        STEP_BARRIER();   // the ONLY barrier per step (lgkm only)
    }
}

// ---------------------------------------------------------------------------
extern "C" void kernel_launch(void* const* d_in, const int* in_sizes, int n_in,
                              void* d_out, int out_size, void* d_ws, size_t ws_size,
                              hipStream_t stream) {
    const float* xs  = (const float*)d_in[0];
    const float* Wih = (const float*)d_in[1];
    const float* Whh = (const float*)d_in[2];
    const float* bih = (const float*)d_in[3];
    const float* bhh = (const float*)d_in[4];
    const float* h0  = (const float*)d_in[5];
    const float* c0  = (const float*)d_in[6];
    float* ys = (float*)d_out;

    const size_t XG_BYTES = (size_t)NSTEP * G4 * sizeof(float);   // 134 MB
    float* xg = (float*)d_ws;
    unsigned long long* slots =
        (unsigned long long*)((char*)d_ws + XG_BYTES);            // 16 KB

    // kill stale tags from previous graph replay (deterministic per call)
    hipMemsetAsync(slots, 0, 2 * HDIM * sizeof(unsigned long long), stream);

    dim3 gridA(G4 / 64, NSTEP / 64);
    gemm_xgates<<<gridA, 256, 0, stream>>>(xs, Wih, bih, bhh, xg);

    void* args[] = {(void*)&xg, (void*)&Whh, (void*)&h0, (void*)&c0,
                    (void*)&ys, (void*)&slots};
    hipLaunchCooperativeKernel((void*)lstm_rec, dim3(REC_G), dim3(REC_T),
                               args, 0, stream);
}